// Round 2
// baseline (2623.430 us; speedup 1.0000x reference)
//
#include <hip/hip_runtime.h>

// ---------------------------------------------------------------------------
// CrossAttention: out = (softmax_causal_masked((xWq)(yWkv_k)^T/8) (yWkv_v)) Wo
// B=4, S=2048, H=1024, NH=16, HD=64
// ---------------------------------------------------------------------------

#define Bv   4
#define Sv   2048
#define Hv   1024
#define NHv  16
#define HDv  64

typedef __attribute__((ext_vector_type(8))) short s16x8;
typedef __attribute__((ext_vector_type(4))) float f32x4;

__device__ __forceinline__ float bf2f(short s) {
  return __uint_as_float(((unsigned)(unsigned short)s) << 16);
}
__device__ __forceinline__ short f2bf(float f) {
  unsigned u = __float_as_uint(f);
  unsigned r = (u + 0x7fffu + ((u >> 16) & 1u)) >> 16;   // RNE
  return (short)r;
}

// ---------------- fp32 -> bf16 convert (vectorized) ------------------------
__global__ __launch_bounds__(256) void cvt_bf16(const float* __restrict__ in,
                                                short* __restrict__ out, int n) {
  int i = (blockIdx.x * 256 + threadIdx.x) * 4;
  if (i < n) {
    float4 v = *(const float4*)&in[i];
    short r0 = f2bf(v.x), r1 = f2bf(v.y), r2 = f2bf(v.z), r3 = f2bf(v.w);
    // pack 4 shorts = 8B store
    unsigned long long pk = (unsigned long long)(unsigned short)r0
                          | ((unsigned long long)(unsigned short)r1 << 16)
                          | ((unsigned long long)(unsigned short)r2 << 32)
                          | ((unsigned long long)(unsigned short)r3 << 48);
    *(unsigned long long*)&out[i] = pk;
  }
}

// ---------------- fp32 [R][C] -> bf16 [C][R] transpose-convert -------------
__global__ __launch_bounds__(256) void tcvt(const float* __restrict__ in,
                                            short* __restrict__ out, int R, int C) {
  __shared__ float tile[32][33];
  int tx = threadIdx.x & 31, ty = threadIdx.x >> 5;  // ty 0..7
  int c0 = blockIdx.x * 32, r0 = blockIdx.y * 32;
#pragma unroll
  for (int i = 0; i < 32; i += 8)
    tile[ty + i][tx] = in[(size_t)(r0 + ty + i) * C + c0 + tx];
  __syncthreads();
#pragma unroll
  for (int i = 0; i < 32; i += 8)
    out[(size_t)(c0 + ty + i) * R + r0 + tx] = f2bf(tile[tx][ty + i]);
}

// ---------------- bf16 GEMM: C[M,N] = A[M,K] * Bt[N,K]^T + bias ------------
// 128x128 tile, BK=64, 4 waves (2x2 of 64x64), mfma_f32_16x16x32_bf16
// MODE 0: scatter bf16 Q[B,NH,S,HD];  MODE 1: scatter bf16 K,V;  MODE 2: fp32 out
template <int MODE>
__global__ __launch_bounds__(256)
void gemm_bt(const short* __restrict__ A, const short* __restrict__ Bt,
             const float* __restrict__ bias, short* __restrict__ out0,
             short* __restrict__ out1, float* __restrict__ outf,
             int M, int N, int K) {
  __shared__ short Alds[128 * 64];
  __shared__ short Blds[128 * 64];
  const int tid = threadIdx.x;
  const int w = tid >> 6, l = tid & 63;
  const int wr = w >> 1, wc = w & 1;
  const int m0 = blockIdx.x * 128, n0 = blockIdx.y * 128;

  f32x4 acc[4][4] = {};

  for (int k0 = 0; k0 < K; k0 += 64) {
    __syncthreads();
#pragma unroll
    for (int i = 0; i < 4; ++i) {
      int chunk = tid + i * 256;              // 0..1023, 8 elems each
      int r = chunk >> 3, c8 = (chunk & 7) << 3;
      *(s16x8*)&Alds[chunk * 8] = *(const s16x8*)&A[(size_t)(m0 + r) * K + k0 + c8];
      *(s16x8*)&Blds[chunk * 8] = *(const s16x8*)&Bt[(size_t)(n0 + r) * K + k0 + c8];
    }
    __syncthreads();
#pragma unroll
    for (int kk = 0; kk < 64; kk += 32) {
      s16x8 af[4], bf[4];
#pragma unroll
      for (int m = 0; m < 4; ++m)
        af[m] = *(s16x8*)&Alds[(wr * 64 + m * 16 + (l & 15)) * 64 + kk + ((l >> 4) << 3)];
#pragma unroll
      for (int n = 0; n < 4; ++n)
        bf[n] = *(s16x8*)&Blds[(wc * 64 + n * 16 + (l & 15)) * 64 + kk + ((l >> 4) << 3)];
#pragma unroll
      for (int m = 0; m < 4; ++m)
#pragma unroll
        for (int n = 0; n < 4; ++n)
          acc[m][n] = __builtin_amdgcn_mfma_f32_16x16x32_bf16(af[m], bf[n], acc[m][n], 0, 0, 0);
    }
  }

  // epilogue: lane l reg e of frag (m,n): row = 4*(l>>4)+e, col = (l&15)
#pragma unroll
  for (int m = 0; m < 4; ++m) {
#pragma unroll
    for (int n = 0; n < 4; ++n) {
#pragma unroll
      for (int e = 0; e < 4; ++e) {
        int gr = m0 + wr * 64 + m * 16 + ((l >> 4) << 2) + e;
        int gc = n0 + wc * 64 + n * 16 + (l & 15);
        float v = acc[m][n][e] + bias[gc];
        if constexpr (MODE == 2) {
          outf[(size_t)gr * N + gc] = v;
        } else if constexpr (MODE == 0) {
          int b = gr >> 11, s = gr & (Sv - 1);
          int h = gc >> 6, d = gc & 63;
          out0[(((size_t)(b * NHv + h)) * Sv + s) * HDv + d] = f2bf(v);
        } else {  // MODE 1: KV
          int b = gr >> 11, s = gr & (Sv - 1);
          int kvi = gc >> 10, cc = gc & 1023;
          int h = cc >> 6, d = cc & 63;
          short* dst = kvi ? out1 : out0;
          dst[(((size_t)(b * NHv + h)) * Sv + s) * HDv + d] = f2bf(v);
        }
      }
    }
  }
}

// ---------------- flash attention (VALU, fp32 accum) -----------------------
// 1 wave / block; each lane owns one q row; K/V 64x64 bf16 tiles in LDS.
__global__ __launch_bounds__(64)
void attn_kernel(const short* __restrict__ Q, const short* __restrict__ Kb,
                 const short* __restrict__ Vb, const unsigned char* __restrict__ msk,
                 short* __restrict__ AO) {
  __shared__ short Klds[64 * 64];
  __shared__ short Vlds[64 * 64];
  const int lane = threadIdx.x;
  const int qt = blockIdx.x & 31;       // S/64 = 32 q-tiles
  const int bh = blockIdx.x >> 5;       // 0..63
  const int b = bh >> 4, h = bh & 15;
  const int q_row = qt * 64 + lane;

  float q[64];
  const short* qp = &Q[((size_t)bh * Sv + q_row) * HDv];
#pragma unroll
  for (int d8 = 0; d8 < 8; ++d8) {
    s16x8 v = *(const s16x8*)&qp[d8 * 8];
#pragma unroll
    for (int e = 0; e < 8; ++e) q[d8 * 8 + e] = bf2f(v[e]) * 0.125f;  // 1/sqrt(64)
  }
  float acc[64];
#pragma unroll
  for (int d = 0; d < 64; ++d) acc[d] = 0.f;
  float mrun = -1e30f, lrun = 0.f;

  for (int kt = 0; kt <= qt; ++kt) {
    __syncthreads();
    const short* kg = &Kb[((size_t)bh * Sv + kt * 64) * HDv];
    const short* vg = &Vb[((size_t)bh * Sv + kt * 64) * HDv];
#pragma unroll
    for (int i = 0; i < 8; ++i) {
      int chunk = lane + i * 64;  // 0..511
      *(s16x8*)&Klds[chunk * 8] = *(const s16x8*)&kg[chunk * 8];
      *(s16x8*)&Vlds[chunk * 8] = *(const s16x8*)&vg[chunk * 8];
    }
    __syncthreads();
    unsigned long long mball = __ballot(msk[b * Sv + kt * 64 + lane] != 0);
    const int jlim = q_row - kt * 64;  // valid jj <= jlim (always >=63 if kt<qt)

    for (int jj = 0; jj < 64; ++jj) {
      float ps[8];
#pragma unroll
      for (int d8 = 0; d8 < 8; ++d8) {
        s16x8 kv = *(s16x8*)&Klds[jj * 64 + d8 * 8];
        float p = 0.f;
#pragma unroll
        for (int e = 0; e < 8; ++e) p += q[d8 * 8 + e] * bf2f(kv[e]);
        ps[d8] = p;
      }
      float s = ((ps[0] + ps[1]) + (ps[2] + ps[3])) + ((ps[4] + ps[5]) + (ps[6] + ps[7]));
      float wgt = 0.f;
      bool ok = (jj <= jlim) && !((mball >> jj) & 1ull);
      if (ok) {
        if (s > mrun + 8.f) {           // defer-max rescale (T13)
          float sc = __expf(mrun - s);
          mrun = s;
          lrun *= sc;
#pragma unroll
          for (int d = 0; d < 64; ++d) acc[d] *= sc;
        }
        wgt = __expf(s - mrun);
        lrun += wgt;
      }
#pragma unroll
      for (int d8 = 0; d8 < 8; ++d8) {
        s16x8 vv = *(s16x8*)&Vlds[jj * 64 + d8 * 8];
#pragma unroll
        for (int e = 0; e < 8; ++e) acc[d8 * 8 + e] += wgt * bf2f(vv[e]);
      }
    }
  }

  float inv = 1.f / lrun;
  short* aop = &AO[((size_t)b * Sv + q_row) * Hv + h * HDv];
#pragma unroll
  for (int d8 = 0; d8 < 8; ++d8) {
    s16x8 t;
#pragma unroll
    for (int e = 0; e < 8; ++e) t[e] = f2bf(acc[d8 * 8 + e] * inv);
    *(s16x8*)&aop[d8 * 8] = t;
  }
}

// ---------------------------------------------------------------------------
extern "C" void kernel_launch(void* const* d_in, const int* in_sizes, int n_in,
                              void* d_out, int out_size, void* d_ws, size_t ws_size,
                              hipStream_t stream) {
  (void)in_sizes; (void)n_in; (void)out_size; (void)ws_size;
  const float* x    = (const float*)d_in[0];
  const float* y    = (const float*)d_in[1];
  const unsigned char* msk = (const unsigned char*)d_in[2];
  const float* Wq   = (const float*)d_in[3];
  const float* Wqb  = (const float*)d_in[4];
  const float* Wkv  = (const float*)d_in[5];
  const float* Wkvb = (const float*)d_in[6];
  const float* Wo   = (const float*)d_in[7];
  const float* Wob  = (const float*)d_in[8];
  float* out = (float*)d_out;

  char* p = (char*)d_ws;
  auto alloc = [&](size_t bytes) {
    char* r = p;
    p += (bytes + 255) & ~(size_t)255;
    return r;
  };
  const size_t MT = (size_t)Bv * Sv;  // 8192
  short* Xb   = (short*)alloc(MT * Hv * 2);
  short* Yb   = (short*)alloc(MT * Hv * 2);
  short* Wqt  = (short*)alloc((size_t)Hv * Hv * 2);
  short* Wkvt = (short*)alloc((size_t)2 * Hv * Hv * 2);
  short* Wot  = (short*)alloc((size_t)Hv * Hv * 2);
  short* Qb   = (short*)alloc(MT * Hv * 2);
  short* Kb   = (short*)alloc(MT * Hv * 2);
  short* Vb   = (short*)alloc(MT * Hv * 2);
  short* AO   = (short*)alloc(MT * Hv * 2);

  const int n_x = (int)(MT * Hv);  // 8388608
  cvt_bf16<<<n_x / 1024, 256, 0, stream>>>(x, Xb, n_x);
  cvt_bf16<<<n_x / 1024, 256, 0, stream>>>(y, Yb, n_x);
  tcvt<<<dim3(Hv / 32, Hv / 32), 256, 0, stream>>>(Wq, Wqt, Hv, Hv);
  tcvt<<<dim3(2 * Hv / 32, Hv / 32), 256, 0, stream>>>(Wkv, Wkvt, Hv, 2 * Hv);
  tcvt<<<dim3(Hv / 32, Hv / 32), 256, 0, stream>>>(Wo, Wot, Hv, Hv);

  gemm_bt<0><<<dim3(MT / 128, Hv / 128), 256, 0, stream>>>(
      Xb, Wqt, Wqb, Qb, nullptr, nullptr, (int)MT, Hv, Hv);
  gemm_bt<1><<<dim3(MT / 128, 2 * Hv / 128), 256, 0, stream>>>(
      Yb, Wkvt, Wkvb, Kb, Vb, nullptr, (int)MT, 2 * Hv, Hv);

  attn_kernel<<<Bv * NHv * (Sv / 64), 64, 0, stream>>>(Qb, Kb, Vb, msk, AO);

  gemm_bt<2><<<dim3(MT / 128, Hv / 128), 256, 0, stream>>>(
      AO, Wot, Wob, nullptr, nullptr, out, (int)MT, Hv, Hv);
}

// Round 4
// 289.198 us; speedup vs baseline: 9.0714x; 9.0714x over previous
//
#include <hip/hip_runtime.h>

// ---------------------------------------------------------------------------
// CrossAttention: out = (softmax_causal_masked((xWq)(yWkv_k)^T/8) (yWkv_v)) Wo
// B=4, S=2048, H=1024, NH=16, HD=64
// ---------------------------------------------------------------------------

#define Bv   4
#define Sv   2048
#define Hv   1024
#define NHv  16
#define HDv  64

typedef __attribute__((ext_vector_type(8))) short s16x8;
typedef __attribute__((ext_vector_type(4))) float f32x4;

__device__ __forceinline__ float bf2f(short s) {
  return __uint_as_float(((unsigned)(unsigned short)s) << 16);
}
__device__ __forceinline__ short f2bf(float f) {
  unsigned u = __float_as_uint(f);
  unsigned r = (u + 0x7fffu + ((u >> 16) & 1u)) >> 16;   // RNE
  return (short)r;
}

// ---------------- fp32 -> bf16 convert (vectorized) ------------------------
__global__ __launch_bounds__(256) void cvt_bf16(const float* __restrict__ in,
                                                short* __restrict__ out, int n) {
  int i = (blockIdx.x * 256 + threadIdx.x) * 4;
  if (i < n) {
    float4 v = *(const float4*)&in[i];
    short r0 = f2bf(v.x), r1 = f2bf(v.y), r2 = f2bf(v.z), r3 = f2bf(v.w);
    unsigned long long pk = (unsigned long long)(unsigned short)r0
                          | ((unsigned long long)(unsigned short)r1 << 16)
                          | ((unsigned long long)(unsigned short)r2 << 32)
                          | ((unsigned long long)(unsigned short)r3 << 48);
    *(unsigned long long*)&out[i] = pk;
  }
}

// ---------------- fp32 [R][C] -> bf16 [C][R] transpose-convert -------------
__global__ __launch_bounds__(256) void tcvt(const float* __restrict__ in,
                                            short* __restrict__ out, int R, int C) {
  __shared__ float tile[32][33];
  int tx = threadIdx.x & 31, ty = threadIdx.x >> 5;  // ty 0..7
  int c0 = blockIdx.x * 32, r0 = blockIdx.y * 32;
#pragma unroll
  for (int i = 0; i < 32; i += 8)
    tile[ty + i][tx] = in[(size_t)(r0 + ty + i) * C + c0 + tx];
  __syncthreads();
#pragma unroll
  for (int i = 0; i < 32; i += 8)
    out[(size_t)(c0 + ty + i) * R + r0 + tx] = f2bf(tile[tx][ty + i]);
}

// ---------------- bf16 GEMM: C[M,N] = A[M,K] * Bt[N,K]^T + bias ------------
// MODE 0: scatter bf16 Q[B,NH,S,HD] pre-scaled by 1/8
// MODE 1: scatter bf16 K[B,NH,S,HD] and V^T[B,NH,HD,S]
// MODE 2: fp32 out
template <int MODE>
__global__ __launch_bounds__(256)
void gemm_bt(const short* __restrict__ A, const short* __restrict__ Bt,
             const float* __restrict__ bias, short* __restrict__ out0,
             short* __restrict__ out1, float* __restrict__ outf,
             int M, int N, int K) {
  __shared__ short Alds[128 * 64];
  __shared__ short Blds[128 * 64];
  const int tid = threadIdx.x;
  const int w = tid >> 6, l = tid & 63;
  const int wr = w >> 1, wc = w & 1;
  const int m0 = blockIdx.x * 128, n0 = blockIdx.y * 128;

  f32x4 acc[4][4] = {};

  for (int k0 = 0; k0 < K; k0 += 64) {
    __syncthreads();
#pragma unroll
    for (int i = 0; i < 4; ++i) {
      int chunk = tid + i * 256;              // 0..1023, 8 elems each
      int r = chunk >> 3, c8 = (chunk & 7) << 3;
      *(s16x8*)&Alds[chunk * 8] = *(const s16x8*)&A[(size_t)(m0 + r) * K + k0 + c8];
      *(s16x8*)&Blds[chunk * 8] = *(const s16x8*)&Bt[(size_t)(n0 + r) * K + k0 + c8];
    }
    __syncthreads();
#pragma unroll
    for (int kk = 0; kk < 64; kk += 32) {
      s16x8 af[4], bf[4];
#pragma unroll
      for (int m = 0; m < 4; ++m)
        af[m] = *(s16x8*)&Alds[(wr * 64 + m * 16 + (l & 15)) * 64 + kk + ((l >> 4) << 3)];
#pragma unroll
      for (int n = 0; n < 4; ++n)
        bf[n] = *(s16x8*)&Blds[(wc * 64 + n * 16 + (l & 15)) * 64 + kk + ((l >> 4) << 3)];
#pragma unroll
      for (int m = 0; m < 4; ++m)
#pragma unroll
        for (int n = 0; n < 4; ++n)
          acc[m][n] = __builtin_amdgcn_mfma_f32_16x16x32_bf16(af[m], bf[n], acc[m][n], 0, 0, 0);
    }
  }

  // epilogue: lane l reg e of frag (m,n): row = 4*(l>>4)+e, col = (l&15)
#pragma unroll
  for (int m = 0; m < 4; ++m) {
#pragma unroll
    for (int n = 0; n < 4; ++n) {
#pragma unroll
      for (int e = 0; e < 4; ++e) {
        int gr = m0 + wr * 64 + m * 16 + ((l >> 4) << 2) + e;
        int gc = n0 + wc * 64 + n * 16 + (l & 15);
        float v = acc[m][n][e] + bias[gc];
        if constexpr (MODE == 2) {
          outf[(size_t)gr * N + gc] = v;
        } else if constexpr (MODE == 0) {
          int b = gr >> 11, s = gr & (Sv - 1);
          int h = gc >> 6, d = gc & 63;
          // pre-scale by 1/sqrt(HD) = 1/8
          out0[(((size_t)(b * NHv + h)) * Sv + s) * HDv + d] = f2bf(v * 0.125f);
        } else {  // MODE 1: K natural, V transposed [bh][d][s]
          int b = gr >> 11, s = gr & (Sv - 1);
          int kvi = gc >> 10, cc = gc & 1023;
          int h = cc >> 6, d = cc & 63;
          if (kvi == 0) {
            out0[(((size_t)(b * NHv + h)) * Sv + s) * HDv + d] = f2bf(v);
          } else {
            out1[(((size_t)(b * NHv + h)) * HDv + d) * Sv + s] = f2bf(v);
          }
        }
      }
    }
  }
}

// ---------------- MFMA flash attention -------------------------------------
// 4 waves x 32 q-rows = 128 q-rows per block. K-tile = 64, staged in LDS
// (XOR-swizzled). Per wave: QK^T (MFMA) -> wave-parallel online softmax
// (shfl_xor row reduce) -> P to per-wave LDS (bf16) -> PV (MFMA).
// Q pre-scaled by 1/8 in projection. V given transposed [bh][d][s].
__global__ __launch_bounds__(256)
void attn_mfma(const short* __restrict__ Q, const short* __restrict__ Kb,
               const short* __restrict__ Vt, const unsigned char* __restrict__ msk,
               short* __restrict__ AO) {
  __shared__ short Klds[64 * 64];        // [k][d], swizzled
  __shared__ short Vlds[64 * 64];        // [d][k], swizzled
  __shared__ short Plds[4 * 32 * 64];    // per-wave [q][k], swizzled
  __shared__ unsigned long long mword;

  const int tid = threadIdx.x;
  const int w = tid >> 6, l = tid & 63;
  const int bh = blockIdx.x & 63;
  const int qb = 15 - (blockIdx.x >> 6);     // heavy q-blocks first
  const int b = bh >> 4, h = bh & 15;
  const int q0 = qb * 128 + w * 32;          // wave's first q row

  // Q fragments, held in registers for the whole kernel: qf[m][kk]
  s16x8 qf[2][2];
  const short* qbase = &Q[((size_t)bh * Sv + q0) * HDv];
#pragma unroll
  for (int m = 0; m < 2; ++m)
#pragma unroll
    for (int kk = 0; kk < 2; ++kk)
      qf[m][kk] = *(const s16x8*)&qbase[(m * 16 + (l & 15)) * 64 + kk * 32 + ((l >> 4) << 3)];

  f32x4 oacc[2][4] = {};
  float mrun[2][4], lrun[2][4];
#pragma unroll
  for (int m = 0; m < 2; ++m)
#pragma unroll
    for (int e = 0; e < 4; ++e) { mrun[m][e] = -1e30f; lrun[m][e] = 0.f; }

  char* const pbase = (char*)Plds + w * 4096;
  const int nkt = qb * 2 + 2;

  for (int kt = 0; kt < nkt; ++kt) {
    const int k0 = kt * 64;
    __syncthreads();   // previous tile fully consumed
    // ---- stage K [k][d] and V^T [d][k] tiles, swizzled ----
    const short* kg = &Kb[((size_t)bh * Sv + k0) * HDv];
    const short* vg = &Vt[(size_t)bh * HDv * Sv + k0];
#pragma unroll
    for (int i = 0; i < 2; ++i) {
      int c = tid + i * 256;                 // 0..511 chunks of 8 elems
      int r = c >> 3, co = (c & 7) << 3;
      int sb = (r * 128 + (c & 7) * 16) ^ ((r & 7) << 4);
      *(s16x8*)((char*)Klds + sb) = *(const s16x8*)&kg[(size_t)r * HDv + co];
      *(s16x8*)((char*)Vlds + sb) = *(const s16x8*)&vg[(size_t)r * Sv + co];
    }
    if (w == 0) {
      unsigned long long mw = __ballot(msk[b * Sv + k0 + l] != 0);
      if (l == 0) mword = mw;
    }
    __syncthreads();

    if (k0 <= q0 + 31) {   // wave has at least one unmasked row in this tile
      // ---- QK^T ----
      f32x4 sacc[2][4] = {};
      __builtin_amdgcn_s_setprio(1);
#pragma unroll
      for (int kk = 0; kk < 2; ++kk) {
        s16x8 kf[4];
#pragma unroll
        for (int n = 0; n < 4; ++n) {
          int row = n * 16 + (l & 15);
          int sb = (row * 128 + kk * 64 + ((l >> 4) << 4)) ^ ((row & 7) << 4);
          kf[n] = *(s16x8*)((char*)Klds + sb);
        }
#pragma unroll
        for (int m = 0; m < 2; ++m)
#pragma unroll
          for (int n = 0; n < 4; ++n)
            sacc[m][n] = __builtin_amdgcn_mfma_f32_16x16x32_bf16(qf[m][kk], kf[n], sacc[m][n], 0, 0, 0);
      }
      __builtin_amdgcn_s_setprio(0);

      // ---- mask + online softmax (wave-parallel) ----
      const unsigned long long mw = mword;
      float p[2][4][4];
#pragma unroll
      for (int m = 0; m < 2; ++m)
#pragma unroll
        for (int n = 0; n < 4; ++n)
#pragma unroll
          for (int e = 0; e < 4; ++e) {
            int kcol = n * 16 + (l & 15);
            int qg = q0 + m * 16 + ((l >> 4) << 2) + e;
            bool bad = (k0 + kcol > qg) || ((mw >> kcol) & 1ull);
            p[m][n][e] = bad ? -1e30f : sacc[m][n][e];
          }
#pragma unroll
      for (int m = 0; m < 2; ++m)
#pragma unroll
        for (int e = 0; e < 4; ++e) {
          float rm = fmaxf(fmaxf(p[m][0][e], p[m][1][e]), fmaxf(p[m][2][e], p[m][3][e]));
          rm = fmaxf(rm, __shfl_xor(rm, 1));
          rm = fmaxf(rm, __shfl_xor(rm, 2));
          rm = fmaxf(rm, __shfl_xor(rm, 4));
          rm = fmaxf(rm, __shfl_xor(rm, 8));
          float nm = fmaxf(mrun[m][e], rm);
          float sc = __expf(mrun[m][e] - nm);
          mrun[m][e] = nm;
          float rs = 0.f;
#pragma unroll
          for (int n = 0; n < 4; ++n) {
            p[m][n][e] = __expf(p[m][n][e] - nm);
            rs += p[m][n][e];
          }
          rs += __shfl_xor(rs, 1);
          rs += __shfl_xor(rs, 2);
          rs += __shfl_xor(rs, 4);
          rs += __shfl_xor(rs, 8);
          lrun[m][e] = lrun[m][e] * sc + rs;
#pragma unroll
          for (int n = 0; n < 4; ++n) oacc[m][n][e] *= sc;
        }

      // ---- P -> per-wave LDS (bf16, swizzled) ----
#pragma unroll
      for (int m = 0; m < 2; ++m)
#pragma unroll
        for (int n = 0; n < 4; ++n)
#pragma unroll
          for (int e = 0; e < 4; ++e) {
            int prow = m * 16 + ((l >> 4) << 2) + e;
            int pcol = n * 16 + (l & 15);
            int sb = (prow * 128 + pcol * 2) ^ ((prow & 7) << 4);
            *(short*)(pbase + sb) = f2bf(p[m][n][e]);
          }

      // ---- PV ----
      __builtin_amdgcn_s_setprio(1);
#pragma unroll
      for (int kk = 0; kk < 2; ++kk) {
        s16x8 pf[2], vf[4];
#pragma unroll
        for (int m = 0; m < 2; ++m) {
          int row = m * 16 + (l & 15);
          int sb = (row * 128 + kk * 64 + ((l >> 4) << 4)) ^ ((row & 7) << 4);
          pf[m] = *(s16x8*)(pbase + sb);
        }
#pragma unroll
        for (int n = 0; n < 4; ++n) {
          int row = n * 16 + (l & 15);
          int sb = (row * 128 + kk * 64 + ((l >> 4) << 4)) ^ ((row & 7) << 4);
          vf[n] = *(s16x8*)((char*)Vlds + sb);
        }
#pragma unroll
        for (int m = 0; m < 2; ++m)
#pragma unroll
          for (int n = 0; n < 4; ++n)
            oacc[m][n] = __builtin_amdgcn_mfma_f32_16x16x32_bf16(pf[m], vf[n], oacc[m][n], 0, 0, 0);
      }
      __builtin_amdgcn_s_setprio(0);
    }
  }

  // ---- epilogue: O /= l, write AO [B,S,H] (bf16) ----
#pragma unroll
  for (int m = 0; m < 2; ++m)
#pragma unroll
    for (int e = 0; e < 4; ++e) {
      float inv = 1.f / lrun[m][e];
#pragma unroll
      for (int n = 0; n < 4; ++n) {
        int qg = q0 + m * 16 + ((l >> 4) << 2) + e;
        int dcol = n * 16 + (l & 15);
        AO[((size_t)b * Sv + qg) * Hv + h * HDv + dcol] = f2bf(oacc[m][n][e] * inv);
      }
    }
}

// ---------------------------------------------------------------------------
extern "C" void kernel_launch(void* const* d_in, const int* in_sizes, int n_in,
                              void* d_out, int out_size, void* d_ws, size_t ws_size,
                              hipStream_t stream) {
  (void)in_sizes; (void)n_in; (void)out_size; (void)ws_size;
  const float* x    = (const float*)d_in[0];
  const float* y    = (const float*)d_in[1];
  const unsigned char* msk = (const unsigned char*)d_in[2];
  const float* Wq   = (const float*)d_in[3];
  const float* Wqb  = (const float*)d_in[4];
  const float* Wkv  = (const float*)d_in[5];
  const float* Wkvb = (const float*)d_in[6];
  const float* Wo   = (const float*)d_in[7];
  const float* Wob  = (const float*)d_in[8];
  float* out = (float*)d_out;

  char* p = (char*)d_ws;
  auto alloc = [&](size_t bytes) {
    char* r = p;
    p += (bytes + 255) & ~(size_t)255;
    return r;
  };
  const size_t MT = (size_t)Bv * Sv;  // 8192
  short* Xb   = (short*)alloc(MT * Hv * 2);
  short* Yb   = (short*)alloc(MT * Hv * 2);
  short* Wqt  = (short*)alloc((size_t)Hv * Hv * 2);
  short* Wkvt = (short*)alloc((size_t)2 * Hv * Hv * 2);
  short* Wot  = (short*)alloc((size_t)Hv * Hv * 2);
  short* Qb   = (short*)alloc(MT * Hv * 2);
  short* Kb   = (short*)alloc(MT * Hv * 2);
  short* Vb   = (short*)alloc(MT * Hv * 2);   // V^T [bh][d][s]
  short* AO   = (short*)alloc(MT * Hv * 2);

  const int n_x = (int)(MT * Hv);  // 8388608
  cvt_bf16<<<n_x / 1024, 256, 0, stream>>>(x, Xb, n_x);
  cvt_bf16<<<n_x / 1024, 256, 0, stream>>>(y, Yb, n_x);
  tcvt<<<dim3(Hv / 32, Hv / 32), 256, 0, stream>>>(Wq, Wqt, Hv, Hv);
  tcvt<<<dim3(2 * Hv / 32, Hv / 32), 256, 0, stream>>>(Wkv, Wkvt, Hv, 2 * Hv);
  tcvt<<<dim3(Hv / 32, Hv / 32), 256, 0, stream>>>(Wo, Wot, Hv, Hv);

  gemm_bt<0><<<dim3(MT / 128, Hv / 128), 256, 0, stream>>>(
      Xb, Wqt, Wqb, Qb, nullptr, nullptr, (int)MT, Hv, Hv);
  gemm_bt<1><<<dim3(MT / 128, 2 * Hv / 128), 256, 0, stream>>>(
      Yb, Wkvt, Wkvb, Kb, Vb, nullptr, (int)MT, 2 * Hv, Hv);

  attn_mfma<<<16 * 64, 256, 0, stream>>>(Qb, Kb, Vb, msk, AO);

  gemm_bt<2><<<dim3(MT / 128, Hv / 128), 256, 0, stream>>>(
      AO, Wot, Wob, nullptr, nullptr, out, (int)MT, Hv, Hv);
}

// Round 5
// 230.394 us; speedup vs baseline: 11.3867x; 1.2552x over previous
//
#include <hip/hip_runtime.h>

// ---------------------------------------------------------------------------
// CrossAttention: out = (softmax_causal_masked((xWq)(yWkv_k)^T/8) (yWkv_v)) Wo
// B=4, S=2048, H=1024, NH=16, HD=64
// ---------------------------------------------------------------------------

#define Bv   4
#define Sv   2048
#define Hv   1024
#define NHv  16
#define HDv  64

typedef __attribute__((ext_vector_type(8))) short s16x8;
typedef __attribute__((ext_vector_type(4))) float f32x4;

__device__ __forceinline__ float bf2f(short s) {
  return __uint_as_float(((unsigned)(unsigned short)s) << 16);
}
__device__ __forceinline__ short f2bf(float f) {   // RNE (for buffers reused as GEMM inputs)
  unsigned u = __float_as_uint(f);
  unsigned r = (u + 0x7fffu + ((u >> 16) & 1u)) >> 16;
  return (short)r;
}

#if __has_builtin(__builtin_amdgcn_exp2f)
#define EXP2(x) __builtin_amdgcn_exp2f(x)
#else
#define EXP2(x) exp2f(x)
#endif

// async global->LDS, 16B per lane (dest must be wave-uniform base + lane*16)
__device__ __forceinline__ void gl_lds16(const short* g, short* l) {
  __builtin_amdgcn_global_load_lds(
      (const __attribute__((address_space(1))) unsigned int*)g,
      (__attribute__((address_space(3))) unsigned int*)l, 16, 0, 0);
}

// ---------------- fp32 -> bf16 convert (vectorized) ------------------------
__global__ __launch_bounds__(256) void cvt_bf16(const float* __restrict__ in,
                                                short* __restrict__ out, int n) {
  int i = (blockIdx.x * 256 + threadIdx.x) * 4;
  if (i < n) {
    float4 v = *(const float4*)&in[i];
    short r0 = f2bf(v.x), r1 = f2bf(v.y), r2 = f2bf(v.z), r3 = f2bf(v.w);
    unsigned long long pk = (unsigned long long)(unsigned short)r0
                          | ((unsigned long long)(unsigned short)r1 << 16)
                          | ((unsigned long long)(unsigned short)r2 << 32)
                          | ((unsigned long long)(unsigned short)r3 << 48);
    *(unsigned long long*)&out[i] = pk;
  }
}

// ---------------- fp32 [R][C] -> bf16 [C][R] transpose-convert -------------
__global__ __launch_bounds__(256) void tcvt(const float* __restrict__ in,
                                            short* __restrict__ out, int R, int C) {
  __shared__ float tile[32][33];
  int tx = threadIdx.x & 31, ty = threadIdx.x >> 5;  // ty 0..7
  int c0 = blockIdx.x * 32, r0 = blockIdx.y * 32;
#pragma unroll
  for (int i = 0; i < 32; i += 8)
    tile[ty + i][tx] = in[(size_t)(r0 + ty + i) * C + c0 + tx];
  __syncthreads();
#pragma unroll
  for (int i = 0; i < 32; i += 8)
    out[(size_t)(c0 + ty + i) * R + r0 + tx] = f2bf(tile[tx][ty + i]);
}

// ---------------- bf16 GEMM: C[M,N] = A[M,K] * Bt[N,K]^T + bias ------------
// 128x128 tile, BK=64, global_load_lds staging (m97 pattern).
// MODE 0: scatter bf16 Q[B,NH,S,HD] pre-scaled by log2e/8
// MODE 1: scatter bf16 K[B,NH,S,HD] and V^T[B,NH,HD,S]
// MODE 2: fp32 out
template <int MODE>
__global__ __launch_bounds__(256)
void gemm_bt(const short* __restrict__ A, const short* __restrict__ Bt,
             const float* __restrict__ bias, short* __restrict__ out0,
             short* __restrict__ out1, float* __restrict__ outf,
             int M, int N, int K) {
  __shared__ short Alds[128 * 64];
  __shared__ short Blds[128 * 64];
  const int tid = threadIdx.x;
  const int w = tid >> 6, l = tid & 63;
  const int wr = w >> 1, wc = w & 1;
  const int m0 = blockIdx.x * 128, n0 = blockIdx.y * 128;

  f32x4 acc[4][4] = {};

  for (int k0 = 0; k0 < K; k0 += 64) {
    __syncthreads();
#pragma unroll
    for (int i = 0; i < 4; ++i) {
      int c = tid + i * 256;                  // 0..1023, 8 elems (16B) each
      int r = c >> 3, co = (c & 7) << 3;
      gl_lds16(&A[(size_t)(m0 + r) * K + k0 + co], &Alds[c * 8]);
      gl_lds16(&Bt[(size_t)(n0 + r) * K + k0 + co], &Blds[c * 8]);
    }
    __syncthreads();   // compiler emits vmcnt(0) drain here
#pragma unroll
    for (int kk = 0; kk < 64; kk += 32) {
      s16x8 af[4], bf[4];
#pragma unroll
      for (int m = 0; m < 4; ++m)
        af[m] = *(s16x8*)&Alds[(wr * 64 + m * 16 + (l & 15)) * 64 + kk + ((l >> 4) << 3)];
#pragma unroll
      for (int n = 0; n < 4; ++n)
        bf[n] = *(s16x8*)&Blds[(wc * 64 + n * 16 + (l & 15)) * 64 + kk + ((l >> 4) << 3)];
#pragma unroll
      for (int m = 0; m < 4; ++m)
#pragma unroll
        for (int n = 0; n < 4; ++n)
          acc[m][n] = __builtin_amdgcn_mfma_f32_16x16x32_bf16(af[m], bf[n], acc[m][n], 0, 0, 0);
    }
  }

  // epilogue: lane l reg e of frag (m,n): row = 4*(l>>4)+e, col = (l&15)
#pragma unroll
  for (int m = 0; m < 4; ++m) {
#pragma unroll
    for (int n = 0; n < 4; ++n) {
#pragma unroll
      for (int e = 0; e < 4; ++e) {
        int gr = m0 + wr * 64 + m * 16 + ((l >> 4) << 2) + e;
        int gc = n0 + wc * 64 + n * 16 + (l & 15);
        float v = acc[m][n][e] + bias[gc];
        if constexpr (MODE == 2) {
          outf[(size_t)gr * N + gc] = v;
        } else if constexpr (MODE == 0) {
          int b = gr >> 11, s = gr & (Sv - 1);
          int h = gc >> 6, d = gc & 63;
          // fold 1/sqrt(HD) * log2(e): attention scores land in log2 units
          out0[(((size_t)(b * NHv + h)) * Sv + s) * HDv + d] = f2bf(v * 0.1803368801f);
        } else {  // MODE 1: K natural, V transposed [bh][d][s]
          int b = gr >> 11, s = gr & (Sv - 1);
          int kvi = gc >> 10, cc = gc & 1023;
          int h = cc >> 6, d = cc & 63;
          if (kvi == 0) {
            out0[(((size_t)(b * NHv + h)) * Sv + s) * HDv + d] = f2bf(v);
          } else {
            out1[(((size_t)(b * NHv + h)) * HDv + d) * Sv + s] = f2bf(v);
          }
        }
      }
    }
  }
}

// ---------------- MFMA flash attention -------------------------------------
// 4 waves x 32 q-rows = 128 q-rows per block. K-tile = 64 via global_load_lds
// (linear dest + pre-swizzled source; reads use the same XOR swizzle).
// Softmax: tile-global max (wave-uniform, 6 shfl) + defer-rescale THR=8;
// row sums via ones-MFMA on the idle matrix pipe. Scores in log2 units
// (log2e folded into Q projection), exp2 direct.
__global__ __launch_bounds__(256)
void attn_mfma(const short* __restrict__ Q, const short* __restrict__ Kb,
               const short* __restrict__ Vt, const unsigned char* __restrict__ msk,
               short* __restrict__ AO) {
  __shared__ short Klds[64 * 64];        // [k][d], swizzled
  __shared__ short Vlds[64 * 64];        // [d][k], swizzled
  __shared__ short Plds[4 * 32 * 64];    // per-wave [q][k], swizzled
  __shared__ unsigned long long mword;

  const int tid = threadIdx.x;
  const int w = tid >> 6, l = tid & 63;
  const int bh = blockIdx.x & 63;
  const int qb = 15 - (blockIdx.x >> 6);     // heavy q-blocks first
  const int b = bh >> 4, h = bh & 15;
  const int q0 = qb * 128 + w * 32;          // wave's first q row

  // Q fragments in registers for the whole kernel (pre-scaled by log2e/8)
  s16x8 qf[2][2];
  const short* qbase = &Q[((size_t)bh * Sv + q0) * HDv];
#pragma unroll
  for (int m = 0; m < 2; ++m)
#pragma unroll
    for (int kk = 0; kk < 2; ++kk)
      qf[m][kk] = *(const s16x8*)&qbase[(m * 16 + (l & 15)) * 64 + kk * 32 + ((l >> 4) << 3)];

  s16x8 onesf;
#pragma unroll
  for (int e2 = 0; e2 < 8; ++e2) onesf[e2] = (short)0x3F80;   // bf16 1.0

  f32x4 oacc[2][4] = {};
  f32x4 lacc[2] = {};            // row sums (col-replicated), from ones-MFMA
  float mrun = -1e30f;           // wave-global running max, log2 units

  char* const pbase = (char*)Plds + w * 4096;
  const int nkt = qb * 2 + 2;

  for (int kt = 0; kt < nkt; ++kt) {
    const int k0 = kt * 64;
    __syncthreads();   // previous tile fully consumed
    // ---- stage K [k][d] and V^T [d][k]: linear LDS dest, pre-swizzled src ----
    const short* kg = &Kb[((size_t)bh * Sv + k0) * HDv];
    const short* vg = &Vt[(size_t)bh * HDv * Sv + k0];
#pragma unroll
    for (int i = 0; i < 2; ++i) {
      int c = tid + i * 256;                  // linear dest chunk (16B)
      int r = c >> 3;
      int u = (c & 7) ^ (r & 7);              // source unit (involution = read swizzle)
      gl_lds16(&kg[(size_t)r * HDv + u * 8], &Klds[c * 8]);
      gl_lds16(&vg[(size_t)r * Sv + u * 8], &Vlds[c * 8]);
    }
    if (w == 0) {
      unsigned long long mwb = __ballot(msk[b * Sv + k0 + l] != 0);
      if (l == 0) mword = mwb;
    }
    __syncthreads();

    if (k0 <= q0 + 31) {   // wave has at least one valid row in this tile
      const unsigned long long mw = mword;
      // ---- QK^T ----
      f32x4 sacc[2][4] = {};
      __builtin_amdgcn_s_setprio(1);
#pragma unroll
      for (int kk = 0; kk < 2; ++kk) {
        s16x8 kf[4];
#pragma unroll
        for (int n = 0; n < 4; ++n) {
          int row = n * 16 + (l & 15);
          int sb = (row * 128 + kk * 64 + ((l >> 4) << 4)) ^ ((row & 7) << 4);
          kf[n] = *(s16x8*)((char*)Klds + sb);
        }
#pragma unroll
        for (int m = 0; m < 2; ++m)
#pragma unroll
          for (int n = 0; n < 4; ++n)
            sacc[m][n] = __builtin_amdgcn_mfma_f32_16x16x32_bf16(qf[m][kk], kf[n], sacc[m][n], 0, 0, 0);
      }
      __builtin_amdgcn_s_setprio(0);

      // ---- mask only where needed (diag tiles or nonzero padding mask) ----
      if ((k0 + 63 > q0) || (mw != 0)) {
#pragma unroll
        for (int m = 0; m < 2; ++m)
#pragma unroll
          for (int n = 0; n < 4; ++n)
#pragma unroll
            for (int e = 0; e < 4; ++e) {
              int kcol = n * 16 + (l & 15);
              int qg = q0 + m * 16 + ((l >> 4) << 2) + e;
              bool bad = (k0 + kcol > qg) || ((mw >> kcol) & 1ull);
              if (bad) sacc[m][n][e] = -1e30f;
            }
      }

      // ---- tile-global max (tree + 6 shfl, wave-uniform result) ----
      float rmn[2][4];
#pragma unroll
      for (int m = 0; m < 2; ++m)
#pragma unroll
        for (int n = 0; n < 4; ++n)
          rmn[m][n] = fmaxf(fmaxf(sacc[m][n][0], sacc[m][n][1]),
                            fmaxf(sacc[m][n][2], sacc[m][n][3]));
      float rm = fmaxf(fmaxf(fmaxf(rmn[0][0], rmn[0][1]), fmaxf(rmn[0][2], rmn[0][3])),
                       fmaxf(fmaxf(rmn[1][0], rmn[1][1]), fmaxf(rmn[1][2], rmn[1][3])));
#pragma unroll
      for (int off = 1; off <= 32; off <<= 1)
        rm = fmaxf(rm, __shfl_xor(rm, off));

      if (rm > -1e29f) {           // tile not fully masked (wave-uniform)
        // ---- defer-rescale (T13), wave-uniform branch ----
        if (rm > mrun + 8.f) {
          float sc = EXP2(mrun - rm);   // first tile: exp2(-inf) = 0
          mrun = rm;
#pragma unroll
          for (int m = 0; m < 2; ++m) {
            lacc[m] *= sc;
#pragma unroll
            for (int n = 0; n < 4; ++n) oacc[m][n] *= sc;
          }
        }

        // ---- P = exp2(s - mrun) -> per-wave LDS (bf16 trunc; normalizer
        //      uses the same bf16 values via ones-MFMA, so bias cancels) ----
#pragma unroll
        for (int m = 0; m < 2; ++m)
#pragma unroll
          for (int n = 0; n < 4; ++n)
#pragma unroll
            for (int e = 0; e < 4; ++e) {
              float pv = EXP2(sacc[m][n][e] - mrun);
              int prow = m * 16 + ((l >> 4) << 2) + e;
              int pcol = n * 16 + (l & 15);
              int sb = (prow * 128 + pcol * 2) ^ ((prow & 7) << 4);
              *(short*)(pbase + sb) = (short)(__float_as_uint(pv) >> 16);
            }

        // ---- PV + row-sums (ones-MFMA) ----
        __builtin_amdgcn_s_setprio(1);
#pragma unroll
        for (int kk = 0; kk < 2; ++kk) {
          s16x8 pf[2], vf[4];
#pragma unroll
          for (int m = 0; m < 2; ++m) {
            int row = m * 16 + (l & 15);
            int sb = (row * 128 + kk * 64 + ((l >> 4) << 4)) ^ ((row & 7) << 4);
            pf[m] = *(s16x8*)(pbase + sb);
          }
#pragma unroll
          for (int n = 0; n < 4; ++n) {
            int row = n * 16 + (l & 15);
            int sb = (row * 128 + kk * 64 + ((l >> 4) << 4)) ^ ((row & 7) << 4);
            vf[n] = *(s16x8*)((char*)Vlds + sb);
          }
#pragma unroll
          for (int m = 0; m < 2; ++m) {
#pragma unroll
            for (int n = 0; n < 4; ++n)
              oacc[m][n] = __builtin_amdgcn_mfma_f32_16x16x32_bf16(pf[m], vf[n], oacc[m][n], 0, 0, 0);
            lacc[m] = __builtin_amdgcn_mfma_f32_16x16x32_bf16(pf[m], onesf, lacc[m], 0, 0, 0);
          }
        }
        __builtin_amdgcn_s_setprio(0);
      }
    }
  }

  // ---- epilogue: O /= rowsum, write AO [B,S,H] (bf16) ----
#pragma unroll
  for (int m = 0; m < 2; ++m)
#pragma unroll
    for (int e = 0; e < 4; ++e) {
      float inv = 1.f / lacc[m][e];
#pragma unroll
      for (int n = 0; n < 4; ++n) {
        int qg = q0 + m * 16 + ((l >> 4) << 2) + e;
        int dcol = n * 16 + (l & 15);
        AO[((size_t)b * Sv + qg) * Hv + h * HDv + dcol] = f2bf(oacc[m][n][e] * inv);
      }
    }
}

// ---------------------------------------------------------------------------
extern "C" void kernel_launch(void* const* d_in, const int* in_sizes, int n_in,
                              void* d_out, int out_size, void* d_ws, size_t ws_size,
                              hipStream_t stream) {
  (void)in_sizes; (void)n_in; (void)out_size; (void)ws_size;
  const float* x    = (const float*)d_in[0];
  const float* y    = (const float*)d_in[1];
  const unsigned char* msk = (const unsigned char*)d_in[2];
  const float* Wq   = (const float*)d_in[3];
  const float* Wqb  = (const float*)d_in[4];
  const float* Wkv  = (const float*)d_in[5];
  const float* Wkvb = (const float*)d_in[6];
  const float* Wo   = (const float*)d_in[7];
  const float* Wob  = (const float*)d_in[8];
  float* out = (float*)d_out;

  char* p = (char*)d_ws;
  auto alloc = [&](size_t bytes) {
    char* r = p;
    p += (bytes + 255) & ~(size_t)255;
    return r;
  };
  const size_t MT = (size_t)Bv * Sv;  // 8192
  short* Xb   = (short*)alloc(MT * Hv * 2);
  short* Yb   = (short*)alloc(MT * Hv * 2);
  short* Wqt  = (short*)alloc((size_t)Hv * Hv * 2);
  short* Wkvt = (short*)alloc((size_t)2 * Hv * Hv * 2);
  short* Wot  = (short*)alloc((size_t)Hv * Hv * 2);
  short* Qb   = (short*)alloc(MT * Hv * 2);
  short* Kb   = (short*)alloc(MT * Hv * 2);
  short* Vb   = (short*)alloc(MT * Hv * 2);   // V^T [bh][d][s]
  short* AO   = (short*)alloc(MT * Hv * 2);

  const int n_x = (int)(MT * Hv);  // 8388608
  cvt_bf16<<<n_x / 1024, 256, 0, stream>>>(x, Xb, n_x);
  cvt_bf16<<<n_x / 1024, 256, 0, stream>>>(y, Yb, n_x);
  tcvt<<<dim3(Hv / 32, Hv / 32), 256, 0, stream>>>(Wq, Wqt, Hv, Hv);
  tcvt<<<dim3(2 * Hv / 32, Hv / 32), 256, 0, stream>>>(Wkv, Wkvt, Hv, 2 * Hv);
  tcvt<<<dim3(Hv / 32, Hv / 32), 256, 0, stream>>>(Wo, Wot, Hv, Hv);

  gemm_bt<0><<<dim3(MT / 128, Hv / 128), 256, 0, stream>>>(
      Xb, Wqt, Wqb, Qb, nullptr, nullptr, (int)MT, Hv, Hv);
  gemm_bt<1><<<dim3(MT / 128, 2 * Hv / 128), 256, 0, stream>>>(
      Yb, Wkvt, Wkvb, Kb, Vb, nullptr, (int)MT, 2 * Hv, Hv);

  attn_mfma<<<16 * 64, 256, 0, stream>>>(Qb, Kb, Vb, msk, AO);

  gemm_bt<2><<<dim3(MT / 128, Hv / 128), 256, 0, stream>>>(
      AO, Wot, Wob, nullptr, nullptr, out, (int)MT, Hv, Hv);
}

// Round 7
// 227.160 us; speedup vs baseline: 11.5488x; 1.0142x over previous
//
#include <hip/hip_runtime.h>

// ---------------------------------------------------------------------------
// CrossAttention: out = (softmax_causal_masked((xWq)(yWkv_k)^T/8) (yWkv_v)) Wo
// B=4, S=2048, H=1024, NH=16, HD=64
// ---------------------------------------------------------------------------

#define Bv   4
#define Sv   2048
#define Hv   1024
#define NHv  16
#define HDv  64

typedef __attribute__((ext_vector_type(8))) short s16x8;
typedef __attribute__((ext_vector_type(4))) float f32x4;

__device__ __forceinline__ float bf2f(short s) {
  return __uint_as_float(((unsigned)(unsigned short)s) << 16);
}
__device__ __forceinline__ short f2bf(float f) {   // RNE
  unsigned u = __float_as_uint(f);
  unsigned r = (u + 0x7fffu + ((u >> 16) & 1u)) >> 16;
  return (short)r;
}

#if __has_builtin(__builtin_amdgcn_exp2f)
#define EXP2(x) __builtin_amdgcn_exp2f(x)
#else
#define EXP2(x) exp2f(x)
#endif

// async global->LDS, 16B per lane (dest = wave-uniform base + lane*16)
__device__ __forceinline__ void gl_lds16(const short* g, short* l) {
  __builtin_amdgcn_global_load_lds(
      (const __attribute__((address_space(1))) unsigned int*)g,
      (__attribute__((address_space(3))) unsigned int*)l, 16, 0, 0);
}

// ---------------- fp32 -> bf16 convert (x and y in one launch) -------------
__global__ __launch_bounds__(256) void cvt2_bf16(const float* __restrict__ x,
                                                 const float* __restrict__ y,
                                                 short* __restrict__ Xb,
                                                 short* __restrict__ Yb, int nper) {
  int half = gridDim.x >> 1;
  int bid = blockIdx.x;
  const float* in = (bid < half) ? x : y;
  short* out = (bid < half) ? Xb : Yb;
  int lb = (bid < half) ? bid : bid - half;
  int i = (lb * 256 + threadIdx.x) * 4;
  if (i < nper) {
    float4 v = *(const float4*)&in[i];
    short r0 = f2bf(v.x), r1 = f2bf(v.y), r2 = f2bf(v.z), r3 = f2bf(v.w);
    unsigned long long pk = (unsigned long long)(unsigned short)r0
                          | ((unsigned long long)(unsigned short)r1 << 16)
                          | ((unsigned long long)(unsigned short)r2 << 32)
                          | ((unsigned long long)(unsigned short)r3 << 48);
    *(unsigned long long*)&out[i] = pk;
  }
}

// ---------------- fp32 [R][C] -> bf16 [C][R] transpose-convert -------------
__global__ __launch_bounds__(256) void tcvt(const float* __restrict__ in,
                                            short* __restrict__ out, int R, int C) {
  __shared__ float tile[32][33];
  int tx = threadIdx.x & 31, ty = threadIdx.x >> 5;  // ty 0..7
  int c0 = blockIdx.x * 32, r0 = blockIdx.y * 32;
#pragma unroll
  for (int i = 0; i < 32; i += 8)
    tile[ty + i][tx] = in[(size_t)(r0 + ty + i) * C + c0 + tx];
  __syncthreads();
#pragma unroll
  for (int i = 0; i < 32; i += 8)
    out[(size_t)(c0 + ty + i) * R + r0 + tx] = f2bf(tile[tx][ty + i]);
}

// ---------------- fused QKV projection GEMM --------------------------------
// C[8192, 3072] where cols 0-1023 = xWq (scatter Q, pre-scaled log2e/8),
// 1024-2047 = yWk (scatter K), 2048-3071 = yWv (scatter V^T).
// A = Xb for col-block < 1024, else Yb. Wt = [3072][1024] bf16 (transposed).
__global__ __launch_bounds__(256)
void gemm_qkv(const short* __restrict__ Xb, const short* __restrict__ Yb,
              const short* __restrict__ Wt, const float* __restrict__ Wqb,
              const float* __restrict__ Wkvb, short* __restrict__ Qb,
              short* __restrict__ Kb, short* __restrict__ Vt) {
  __shared__ short Alds[128 * 64];
  __shared__ short Blds[128 * 64];
  const int tid = threadIdx.x;
  const int w = tid >> 6, l = tid & 63;
  const int wr = w >> 1, wc = w & 1;
  const int m0 = blockIdx.x * 128, n0 = blockIdx.y * 128;
  const short* A = (n0 < 1024) ? Xb : Yb;
  const int K = Hv;

  f32x4 acc[4][4] = {};

  for (int k0 = 0; k0 < K; k0 += 64) {
    __syncthreads();
#pragma unroll
    for (int i = 0; i < 4; ++i) {
      int c = tid + i * 256;
      int r = c >> 3, co = (c & 7) << 3;
      gl_lds16(&A[(size_t)(m0 + r) * K + k0 + co], &Alds[c * 8]);
      gl_lds16(&Wt[(size_t)(n0 + r) * K + k0 + co], &Blds[c * 8]);
    }
    __syncthreads();
#pragma unroll
    for (int kk = 0; kk < 64; kk += 32) {
      s16x8 af[4], bf[4];
#pragma unroll
      for (int m = 0; m < 4; ++m)
        af[m] = *(s16x8*)&Alds[(wr * 64 + m * 16 + (l & 15)) * 64 + kk + ((l >> 4) << 3)];
#pragma unroll
      for (int n = 0; n < 4; ++n)
        bf[n] = *(s16x8*)&Blds[(wc * 64 + n * 16 + (l & 15)) * 64 + kk + ((l >> 4) << 3)];
#pragma unroll
      for (int m = 0; m < 4; ++m)
#pragma unroll
        for (int n = 0; n < 4; ++n)
          acc[m][n] = __builtin_amdgcn_mfma_f32_16x16x32_bf16(af[m], bf[n], acc[m][n], 0, 0, 0);
    }
  }

#pragma unroll
  for (int m = 0; m < 4; ++m) {
#pragma unroll
    for (int n = 0; n < 4; ++n) {
#pragma unroll
      for (int e = 0; e < 4; ++e) {
        int gr = m0 + wr * 64 + m * 16 + ((l >> 4) << 2) + e;
        int gc = n0 + wc * 64 + n * 16 + (l & 15);
        float v = acc[m][n][e] + (gc < 1024 ? Wqb[gc] : Wkvb[gc - 1024]);
        int b = gr >> 11, s = gr & (Sv - 1);
        int sel = gc >> 10, cc = gc & 1023;
        int h = cc >> 6, d = cc & 63;
        if (sel == 0) {
          // fold 1/sqrt(HD) * log2(e): scores in log2 units
          Qb[(((size_t)(b * NHv + h)) * Sv + s) * HDv + d] = f2bf(v * 0.1803368801f);
        } else if (sel == 1) {
          Kb[(((size_t)(b * NHv + h)) * Sv + s) * HDv + d] = f2bf(v);
        } else {
          Vt[(((size_t)(b * NHv + h)) * HDv + d) * Sv + s] = f2bf(v);
        }
      }
    }
  }
}

// ---------------- output projection GEMM (fp32 out) ------------------------
__global__ __launch_bounds__(256)
void gemm_out(const short* __restrict__ A, const short* __restrict__ Bt,
              const float* __restrict__ bias, float* __restrict__ outf,
              int M, int N, int K) {
  __shared__ short Alds[128 * 64];
  __shared__ short Blds[128 * 64];
  const int tid = threadIdx.x;
  const int w = tid >> 6, l = tid & 63;
  const int wr = w >> 1, wc = w & 1;
  const int m0 = blockIdx.x * 128, n0 = blockIdx.y * 128;

  f32x4 acc[4][4] = {};

  for (int k0 = 0; k0 < K; k0 += 64) {
    __syncthreads();
#pragma unroll
    for (int i = 0; i < 4; ++i) {
      int c = tid + i * 256;
      int r = c >> 3, co = (c & 7) << 3;
      gl_lds16(&A[(size_t)(m0 + r) * K + k0 + co], &Alds[c * 8]);
      gl_lds16(&Bt[(size_t)(n0 + r) * K + k0 + co], &Blds[c * 8]);
    }
    __syncthreads();
#pragma unroll
    for (int kk = 0; kk < 64; kk += 32) {
      s16x8 af[4], bf[4];
#pragma unroll
      for (int m = 0; m < 4; ++m)
        af[m] = *(s16x8*)&Alds[(wr * 64 + m * 16 + (l & 15)) * 64 + kk + ((l >> 4) << 3)];
#pragma unroll
      for (int n = 0; n < 4; ++n)
        bf[n] = *(s16x8*)&Blds[(wc * 64 + n * 16 + (l & 15)) * 64 + kk + ((l >> 4) << 3)];
#pragma unroll
      for (int m = 0; m < 4; ++m)
#pragma unroll
        for (int n = 0; n < 4; ++n)
          acc[m][n] = __builtin_amdgcn_mfma_f32_16x16x32_bf16(af[m], bf[n], acc[m][n], 0, 0, 0);
    }
  }

#pragma unroll
  for (int m = 0; m < 4; ++m)
#pragma unroll
    for (int n = 0; n < 4; ++n)
#pragma unroll
      for (int e = 0; e < 4; ++e) {
        int gr = m0 + wr * 64 + m * 16 + ((l >> 4) << 2) + e;
        int gc = n0 + wc * 64 + n * 16 + (l & 15);
        outf[(size_t)gr * N + gc] = acc[m][n][e] + bias[gc];
      }
}

// ---------------- MFMA flash attention, 2-phase K/V double-buffer ----------
// 4 waves x 32 q-rows = 128 q-rows per block. K-tile 64. Stage tile t+1
// (global_load_lds, pre-swizzled source) BEFORE computing tile t; single
// barrier per tile (its vmcnt(0) drain lands after compute covers latency).
__global__ __launch_bounds__(256)
void attn_mfma(const short* __restrict__ Q, const short* __restrict__ Kb,
               const short* __restrict__ Vt, const unsigned char* __restrict__ msk,
               short* __restrict__ AO) {
  __shared__ short Klds[2][64 * 64];     // [k][d], swizzled
  __shared__ short Vlds[2][64 * 64];     // [d][k], swizzled
  __shared__ short Plds[4 * 32 * 64];    // per-wave [q][k], swizzled
  __shared__ unsigned long long mword[2];

  const int tid = threadIdx.x;
  const int w = tid >> 6, l = tid & 63;
  const int bh = blockIdx.x & 63;
  const int qb = 15 - (blockIdx.x >> 6);     // heavy q-blocks first
  const int b = bh >> 4, h = bh & 15;
  const int q0 = qb * 128 + w * 32;          // wave's first q row

  // Q fragments in registers (pre-scaled by log2e/8)
  s16x8 qf[2][2];
  const short* qbase = &Q[((size_t)bh * Sv + q0) * HDv];
#pragma unroll
  for (int m = 0; m < 2; ++m)
#pragma unroll
    for (int kk = 0; kk < 2; ++kk)
      qf[m][kk] = *(const s16x8*)&qbase[(m * 16 + (l & 15)) * 64 + kk * 32 + ((l >> 4) << 3)];

  s16x8 onesf;
#pragma unroll
  for (int e2 = 0; e2 < 8; ++e2) onesf[e2] = (short)0x3F80;   // bf16 1.0

  f32x4 oacc[2][4] = {};
  f32x4 lacc[2] = {};            // row sums via ones-MFMA
  float mrun = -1e30f;           // wave-global running max, log2 units

  char* const pbase = (char*)Plds + w * 4096;
  const short* kg0 = &Kb[(size_t)bh * Sv * HDv];
  const short* vg0 = &Vt[(size_t)bh * HDv * Sv];
  const int nkt = qb * 2 + 2;

  auto stageKV = [&](int t, int bufi) {
    const short* kg = kg0 + (size_t)t * 64 * HDv;
    const short* vg = vg0 + t * 64;
#pragma unroll
    for (int i = 0; i < 2; ++i) {
      int c = tid + i * 256;                  // linear dest chunk (16B)
      int r = c >> 3;
      int u = (c & 7) ^ (r & 7);              // pre-swizzled source (involution)
      gl_lds16(&kg[(size_t)r * HDv + u * 8], &Klds[bufi][c * 8]);
      gl_lds16(&vg[(size_t)r * Sv + u * 8], &Vlds[bufi][c * 8]);
    }
  };

  // prologue: stage tile 0
  stageKV(0, 0);
  if (w == 0) {
    unsigned long long mwb = __ballot(msk[b * Sv + l] != 0);
    if (l == 0) mword[0] = mwb;
  }
  __syncthreads();

  for (int kt = 0; kt < nkt; ++kt) {
    const int k0 = kt * 64;
    const int buf = kt & 1;
    // ---- prefetch tile kt+1 into the other buffer ----
    if (kt + 1 < nkt) {
      stageKV(kt + 1, buf ^ 1);
      if (w == 0) {
        unsigned long long mwb = __ballot(msk[b * Sv + (kt + 1) * 64 + l] != 0);
        if (l == 0) mword[buf ^ 1] = mwb;
      }
    }

    if (k0 <= q0 + 31) {   // wave has at least one valid row in this tile
      const unsigned long long mw = mword[buf];
      const char* kldsb = (const char*)Klds[buf];
      const char* vldsb = (const char*)Vlds[buf];
      // ---- QK^T ----
      f32x4 sacc[2][4] = {};
      __builtin_amdgcn_s_setprio(1);
#pragma unroll
      for (int kk = 0; kk < 2; ++kk) {
        s16x8 kf[4];
#pragma unroll
        for (int n = 0; n < 4; ++n) {
          int row = n * 16 + (l & 15);
          int sb = (row * 128 + kk * 64 + ((l >> 4) << 4)) ^ ((row & 7) << 4);
          kf[n] = *(s16x8*)(kldsb + sb);
        }
#pragma unroll
        for (int m = 0; m < 2; ++m)
#pragma unroll
          for (int n = 0; n < 4; ++n)
            sacc[m][n] = __builtin_amdgcn_mfma_f32_16x16x32_bf16(qf[m][kk], kf[n], sacc[m][n], 0, 0, 0);
      }
      __builtin_amdgcn_s_setprio(0);

      // ---- mask only where needed ----
      if ((k0 + 63 > q0) || (mw != 0)) {
#pragma unroll
        for (int m = 0; m < 2; ++m)
#pragma unroll
          for (int n = 0; n < 4; ++n)
#pragma unroll
            for (int e = 0; e < 4; ++e) {
              int kcol = n * 16 + (l & 15);
              int qg = q0 + m * 16 + ((l >> 4) << 2) + e;
              bool bad = (k0 + kcol > qg) || ((mw >> kcol) & 1ull);
              if (bad) sacc[m][n][e] = -1e30f;
            }
      }

      // ---- tile-global max (tree + 6 shfl, wave-uniform) ----
      float rmn[2][4];
#pragma unroll
      for (int m = 0; m < 2; ++m)
#pragma unroll
        for (int n = 0; n < 4; ++n)
          rmn[m][n] = fmaxf(fmaxf(sacc[m][n][0], sacc[m][n][1]),
                            fmaxf(sacc[m][n][2], sacc[m][n][3]));
      float rm = fmaxf(fmaxf(fmaxf(rmn[0][0], rmn[0][1]), fmaxf(rmn[0][2], rmn[0][3])),
                       fmaxf(fmaxf(rmn[1][0], rmn[1][1]), fmaxf(rmn[1][2], rmn[1][3])));
#pragma unroll
      for (int off = 1; off <= 32; off <<= 1)
        rm = fmaxf(rm, __shfl_xor(rm, off));

      if (rm > -1e29f) {           // tile not fully masked (wave-uniform)
        // ---- defer-rescale (T13) ----
        if (rm > mrun + 8.f) {
          float sc = EXP2(mrun - rm);   // first tile: 0
          mrun = rm;
#pragma unroll
          for (int m = 0; m < 2; ++m) {
            lacc[m] *= sc;
#pragma unroll
            for (int n = 0; n < 4; ++n) oacc[m][n] *= sc;
          }
        }

        // ---- P = exp2(s - mrun) -> per-wave LDS (bf16 trunc) ----
#pragma unroll
        for (int m = 0; m < 2; ++m)
#pragma unroll
          for (int n = 0; n < 4; ++n)
#pragma unroll
            for (int e = 0; e < 4; ++e) {
              float pv = EXP2(sacc[m][n][e] - mrun);
              int prow = m * 16 + ((l >> 4) << 2) + e;
              int pcol = n * 16 + (l & 15);
              int sb = (prow * 128 + pcol * 2) ^ ((prow & 7) << 4);
              *(short*)(pbase + sb) = (short)(__float_as_uint(pv) >> 16);
            }

        // ---- PV + row-sums (ones-MFMA) ----
        __builtin_amdgcn_s_setprio(1);
#pragma unroll
        for (int kk = 0; kk < 2; ++kk) {
          s16x8 pf[2], vf[4];
#pragma unroll
          for (int m = 0; m < 2; ++m) {
            int row = m * 16 + (l & 15);
            int sb = (row * 128 + kk * 64 + ((l >> 4) << 4)) ^ ((row & 7) << 4);
            pf[m] = *(s16x8*)(pbase + sb);
          }
#pragma unroll
          for (int n = 0; n < 4; ++n) {
            int row = n * 16 + (l & 15);
            int sb = (row * 128 + kk * 64 + ((l >> 4) << 4)) ^ ((row & 7) << 4);
            vf[n] = *(s16x8*)(vldsb + sb);
          }
#pragma unroll
          for (int m = 0; m < 2; ++m) {
#pragma unroll
            for (int n = 0; n < 4; ++n)
              oacc[m][n] = __builtin_amdgcn_mfma_f32_16x16x32_bf16(pf[m], vf[n], oacc[m][n], 0, 0, 0);
            lacc[m] = __builtin_amdgcn_mfma_f32_16x16x32_bf16(pf[m], onesf, lacc[m], 0, 0, 0);
          }
        }
        __builtin_amdgcn_s_setprio(0);
      }
    }
    __syncthreads();   // stage(kt+1) drained; all waves done with buf
  }

  // ---- epilogue: O /= rowsum, write AO [B,S,H] (bf16) ----
#pragma unroll
  for (int m = 0; m < 2; ++m)
#pragma unroll
    for (int e = 0; e < 4; ++e) {
      float inv = 1.f / lacc[m][e];
#pragma unroll
      for (int n = 0; n < 4; ++n) {
        int qg = q0 + m * 16 + ((l >> 4) << 2) + e;
        int dcol = n * 16 + (l & 15);
        AO[((size_t)b * Sv + qg) * Hv + h * HDv + dcol] = f2bf(oacc[m][n][e] * inv);
      }
    }
}

// ---------------------------------------------------------------------------
extern "C" void kernel_launch(void* const* d_in, const int* in_sizes, int n_in,
                              void* d_out, int out_size, void* d_ws, size_t ws_size,
                              hipStream_t stream) {
  (void)in_sizes; (void)n_in; (void)out_size; (void)ws_size;
  const float* x    = (const float*)d_in[0];
  const float* y    = (const float*)d_in[1];
  const unsigned char* msk = (const unsigned char*)d_in[2];
  const float* Wq   = (const float*)d_in[3];
  const float* Wqb  = (const float*)d_in[4];
  const float* Wkv  = (const float*)d_in[5];
  const float* Wkvb = (const float*)d_in[6];
  const float* Wo   = (const float*)d_in[7];
  const float* Wob  = (const float*)d_in[8];
  float* out = (float*)d_out;

  char* p = (char*)d_ws;
  auto alloc = [&](size_t bytes) {
    char* r = p;
    p += (bytes + 255) & ~(size_t)255;
    return r;
  };
  const size_t MT = (size_t)Bv * Sv;  // 8192
  short* Xb   = (short*)alloc(MT * Hv * 2);
  short* Yb   = (short*)alloc(MT * Hv * 2);
  short* Wt   = (short*)alloc((size_t)3 * Hv * Hv * 2);   // [Wq^T | Wkv^T] rows 0-3071
  short* Wot  = (short*)alloc((size_t)Hv * Hv * 2);
  short* Qb   = (short*)alloc(MT * Hv * 2);
  short* Kb   = (short*)alloc(MT * Hv * 2);
  short* Vb   = (short*)alloc(MT * Hv * 2);   // V^T [bh][d][s]
  short* AO   = (short*)alloc(MT * Hv * 2);

  const int n_x = (int)(MT * Hv);  // 8388608
  cvt2_bf16<<<2 * (n_x / 1024), 256, 0, stream>>>(x, y, Xb, Yb, n_x);
  tcvt<<<dim3(Hv / 32, Hv / 32), 256, 0, stream>>>(Wq, Wt, Hv, Hv);
  tcvt<<<dim3(2 * Hv / 32, Hv / 32), 256, 0, stream>>>(Wkv, Wt + (size_t)Hv * Hv, Hv, 2 * Hv);
  tcvt<<<dim3(Hv / 32, Hv / 32), 256, 0, stream>>>(Wo, Wot, Hv, Hv);

  gemm_qkv<<<dim3(MT / 128, 3 * Hv / 128), 256, 0, stream>>>(
      Xb, Yb, Wt, Wqb, Wkvb, Qb, Kb, Vb);

  attn_mfma<<<16 * 64, 256, 0, stream>>>(Qb, Kb, Vb, msk, AO);

  gemm_out<<<dim3(MT / 128, Hv / 128), 256, 0, stream>>>(
      AO, Wot, Wob, out, (int)MT, Hv, Hv);
}

// Round 8
// 209.685 us; speedup vs baseline: 12.5113x; 1.0833x over previous
//
#include <hip/hip_runtime.h>

// ---------------------------------------------------------------------------
// CrossAttention: out = (softmax_causal_masked((xWq)(yWkv_k)^T/8) (yWkv_v)) Wo
// B=4, S=2048, H=1024, NH=16, HD=64
// ---------------------------------------------------------------------------

#define Bv   4
#define Sv   2048
#define Hv   1024
#define NHv  16
#define HDv  64

typedef __attribute__((ext_vector_type(8))) short s16x8;
typedef __attribute__((ext_vector_type(4))) float f32x4;

__device__ __forceinline__ float bf2f(short s) {
  return __uint_as_float(((unsigned)(unsigned short)s) << 16);
}
__device__ __forceinline__ short f2bf(float f) {   // RNE
  unsigned u = __float_as_uint(f);
  unsigned r = (u + 0x7fffu + ((u >> 16) & 1u)) >> 16;
  return (short)r;
}

#if __has_builtin(__builtin_amdgcn_exp2f)
#define EXP2(x) __builtin_amdgcn_exp2f(x)
#else
#define EXP2(x) exp2f(x)
#endif

// async global->LDS, 16B per lane (dest = wave-uniform base + lane*16)
__device__ __forceinline__ void gl_lds16(const short* g, short* l) {
  __builtin_amdgcn_global_load_lds(
      (const __attribute__((address_space(1))) unsigned int*)g,
      (__attribute__((address_space(3))) unsigned int*)l, 16, 0, 0);
}

// ---------------- fp32 -> bf16 convert (x and y in one launch) -------------
__global__ __launch_bounds__(256) void cvt2_bf16(const float* __restrict__ x,
                                                 const float* __restrict__ y,
                                                 short* __restrict__ Xb,
                                                 short* __restrict__ Yb, int nper) {
  int half = gridDim.x >> 1;
  int bid = blockIdx.x;
  const float* in = (bid < half) ? x : y;
  short* out = (bid < half) ? Xb : Yb;
  int lb = (bid < half) ? bid : bid - half;
  int i = (lb * 256 + threadIdx.x) * 4;
  if (i < nper) {
    float4 v = *(const float4*)&in[i];
    short r0 = f2bf(v.x), r1 = f2bf(v.y), r2 = f2bf(v.z), r3 = f2bf(v.w);
    unsigned long long pk = (unsigned long long)(unsigned short)r0
                          | ((unsigned long long)(unsigned short)r1 << 16)
                          | ((unsigned long long)(unsigned short)r2 << 32)
                          | ((unsigned long long)(unsigned short)r3 << 48);
    *(unsigned long long*)&out[i] = pk;
  }
}

// ---------------- fp32 [R][C] -> bf16 [C][R] transpose-convert -------------
__global__ __launch_bounds__(256) void tcvt(const float* __restrict__ in,
                                            short* __restrict__ out, int R, int C) {
  __shared__ float tile[32][33];
  int tx = threadIdx.x & 31, ty = threadIdx.x >> 5;  // ty 0..7
  int c0 = blockIdx.x * 32, r0 = blockIdx.y * 32;
#pragma unroll
  for (int i = 0; i < 32; i += 8)
    tile[ty + i][tx] = in[(size_t)(r0 + ty + i) * C + c0 + tx];
  __syncthreads();
#pragma unroll
  for (int i = 0; i < 32; i += 8)
    out[(size_t)(c0 + ty + i) * R + r0 + tx] = f2bf(tile[tx][ty + i]);
}

// ---------------- fused QKV projection GEMM --------------------------------
// C[8192, 3072]: cols 0-1023 = xWq (scatter Q, pre-scaled log2e/8),
// 1024-2047 = yWk (scatter K), 2048-3071 = yWv (scatter V^T).
// T2 LDS swizzle: linear gl_lds dest + pre-swizzled source (u = j^(r&7)),
// reads XOR byte offset with (row&7)<<4  ->  2-way conflicts only (free).
__global__ __launch_bounds__(256)
void gemm_qkv(const short* __restrict__ Xb, const short* __restrict__ Yb,
              const short* __restrict__ Wt, const float* __restrict__ Wqb,
              const float* __restrict__ Wkvb, short* __restrict__ Qb,
              short* __restrict__ Kb, short* __restrict__ Vt) {
  __shared__ short Alds[128 * 64];
  __shared__ short Blds[128 * 64];
  const int tid = threadIdx.x;
  const int w = tid >> 6, l = tid & 63;
  const int wr = w >> 1, wc = w & 1;
  const int m0 = blockIdx.x * 128, n0 = blockIdx.y * 128;
  const short* A = (n0 < 1024) ? Xb : Yb;
  const int K = Hv;

  f32x4 acc[4][4] = {};

  for (int k0 = 0; k0 < K; k0 += 64) {
    __syncthreads();
#pragma unroll
    for (int i = 0; i < 4; ++i) {
      int c = tid + i * 256;                  // linear dest chunk (16B)
      int r = c >> 3;
      int u = (c & 7) ^ (r & 7);              // pre-swizzled source unit
      gl_lds16(&A[(size_t)(m0 + r) * K + k0 + u * 8], &Alds[c * 8]);
      gl_lds16(&Wt[(size_t)(n0 + r) * K + k0 + u * 8], &Blds[c * 8]);
    }
    __syncthreads();
#pragma unroll
    for (int kk = 0; kk < 64; kk += 32) {
      s16x8 af[4], bf[4];
#pragma unroll
      for (int m = 0; m < 4; ++m) {
        int row = wr * 64 + m * 16 + (l & 15);
        int sb = (row * 128 + kk * 2 + ((l >> 4) << 4)) ^ ((row & 7) << 4);
        af[m] = *(s16x8*)((char*)Alds + sb);
      }
#pragma unroll
      for (int n = 0; n < 4; ++n) {
        int row = wc * 64 + n * 16 + (l & 15);
        int sb = (row * 128 + kk * 2 + ((l >> 4) << 4)) ^ ((row & 7) << 4);
        bf[n] = *(s16x8*)((char*)Blds + sb);
      }
#pragma unroll
      for (int m = 0; m < 4; ++m)
#pragma unroll
        for (int n = 0; n < 4; ++n)
          acc[m][n] = __builtin_amdgcn_mfma_f32_16x16x32_bf16(af[m], bf[n], acc[m][n], 0, 0, 0);
    }
  }

#pragma unroll
  for (int m = 0; m < 4; ++m) {
#pragma unroll
    for (int n = 0; n < 4; ++n) {
#pragma unroll
      for (int e = 0; e < 4; ++e) {
        int gr = m0 + wr * 64 + m * 16 + ((l >> 4) << 2) + e;
        int gc = n0 + wc * 64 + n * 16 + (l & 15);
        float v = acc[m][n][e] + (gc < 1024 ? Wqb[gc] : Wkvb[gc - 1024]);
        int b = gr >> 11, s = gr & (Sv - 1);
        int sel = gc >> 10, cc = gc & 1023;
        int h = cc >> 6, d = cc & 63;
        if (sel == 0) {
          // fold 1/sqrt(HD) * log2(e): scores in log2 units
          Qb[(((size_t)(b * NHv + h)) * Sv + s) * HDv + d] = f2bf(v * 0.1803368801f);
        } else if (sel == 1) {
          Kb[(((size_t)(b * NHv + h)) * Sv + s) * HDv + d] = f2bf(v);
        } else {
          Vt[(((size_t)(b * NHv + h)) * HDv + d) * Sv + s] = f2bf(v);
        }
      }
    }
  }
}

// ---------------- output projection GEMM (fp32 out), T2-swizzled -----------
__global__ __launch_bounds__(256)
void gemm_out(const short* __restrict__ A, const short* __restrict__ Bt,
              const float* __restrict__ bias, float* __restrict__ outf,
              int M, int N, int K) {
  __shared__ short Alds[128 * 64];
  __shared__ short Blds[128 * 64];
  const int tid = threadIdx.x;
  const int w = tid >> 6, l = tid & 63;
  const int wr = w >> 1, wc = w & 1;
  const int m0 = blockIdx.x * 128, n0 = blockIdx.y * 128;

  f32x4 acc[4][4] = {};

  for (int k0 = 0; k0 < K; k0 += 64) {
    __syncthreads();
#pragma unroll
    for (int i = 0; i < 4; ++i) {
      int c = tid + i * 256;
      int r = c >> 3;
      int u = (c & 7) ^ (r & 7);
      gl_lds16(&A[(size_t)(m0 + r) * K + k0 + u * 8], &Alds[c * 8]);
      gl_lds16(&Bt[(size_t)(n0 + r) * K + k0 + u * 8], &Blds[c * 8]);
    }
    __syncthreads();
#pragma unroll
    for (int kk = 0; kk < 64; kk += 32) {
      s16x8 af[4], bf[4];
#pragma unroll
      for (int m = 0; m < 4; ++m) {
        int row = wr * 64 + m * 16 + (l & 15);
        int sb = (row * 128 + kk * 2 + ((l >> 4) << 4)) ^ ((row & 7) << 4);
        af[m] = *(s16x8*)((char*)Alds + sb);
      }
#pragma unroll
      for (int n = 0; n < 4; ++n) {
        int row = wc * 64 + n * 16 + (l & 15);
        int sb = (row * 128 + kk * 2 + ((l >> 4) << 4)) ^ ((row & 7) << 4);
        bf[n] = *(s16x8*)((char*)Blds + sb);
      }
#pragma unroll
      for (int m = 0; m < 4; ++m)
#pragma unroll
        for (int n = 0; n < 4; ++n)
          acc[m][n] = __builtin_amdgcn_mfma_f32_16x16x32_bf16(af[m], bf[n], acc[m][n], 0, 0, 0);
    }
  }

#pragma unroll
  for (int m = 0; m < 4; ++m)
#pragma unroll
    for (int n = 0; n < 4; ++n)
#pragma unroll
      for (int e = 0; e < 4; ++e) {
        int gr = m0 + wr * 64 + m * 16 + ((l >> 4) << 2) + e;
        int gc = n0 + wc * 64 + n * 16 + (l & 15);
        outf[(size_t)gr * N + gc] = acc[m][n][e] + bias[gc];
      }
}

// ---------------- MFMA flash attention, 2-phase K/V double-buffer ----------
// 4 waves x 32 q-rows = 128 q-rows per block. K-tile 64. Stage tile t+1
// (global_load_lds, pre-swizzled source) BEFORE computing tile t; single
// barrier per tile (its vmcnt(0) drain lands after compute covers latency).
__global__ __launch_bounds__(256)
void attn_mfma(const short* __restrict__ Q, const short* __restrict__ Kb,
               const short* __restrict__ Vt, const unsigned char* __restrict__ msk,
               short* __restrict__ AO) {
  __shared__ short Klds[2][64 * 64];     // [k][d], swizzled
  __shared__ short Vlds[2][64 * 64];     // [d][k], swizzled
  __shared__ short Plds[4 * 32 * 64];    // per-wave [q][k], swizzled
  __shared__ unsigned long long mword[2];

  const int tid = threadIdx.x;
  const int w = tid >> 6, l = tid & 63;
  const int bh = blockIdx.x & 63;
  const int qb = 15 - (blockIdx.x >> 6);     // heavy q-blocks first
  const int b = bh >> 4, h = bh & 15;
  const int q0 = qb * 128 + w * 32;          // wave's first q row

  // Q fragments in registers (pre-scaled by log2e/8)
  s16x8 qf[2][2];
  const short* qbase = &Q[((size_t)bh * Sv + q0) * HDv];
#pragma unroll
  for (int m = 0; m < 2; ++m)
#pragma unroll
    for (int kk = 0; kk < 2; ++kk)
      qf[m][kk] = *(const s16x8*)&qbase[(m * 16 + (l & 15)) * 64 + kk * 32 + ((l >> 4) << 3)];

  s16x8 onesf;
#pragma unroll
  for (int e2 = 0; e2 < 8; ++e2) onesf[e2] = (short)0x3F80;   // bf16 1.0

  f32x4 oacc[2][4] = {};
  f32x4 lacc[2] = {};            // row sums via ones-MFMA
  float mrun = -1e30f;           // wave-global running max, log2 units

  char* const pbase = (char*)Plds + w * 4096;
  const short* kg0 = &Kb[(size_t)bh * Sv * HDv];
  const short* vg0 = &Vt[(size_t)bh * HDv * Sv];
  const int nkt = qb * 2 + 2;

  auto stageKV = [&](int t, int bufi) {
    const short* kg = kg0 + (size_t)t * 64 * HDv;
    const short* vg = vg0 + t * 64;
#pragma unroll
    for (int i = 0; i < 2; ++i) {
      int c = tid + i * 256;                  // linear dest chunk (16B)
      int r = c >> 3;
      int u = (c & 7) ^ (r & 7);              // pre-swizzled source (involution)
      gl_lds16(&kg[(size_t)r * HDv + u * 8], &Klds[bufi][c * 8]);
      gl_lds16(&vg[(size_t)r * Sv + u * 8], &Vlds[bufi][c * 8]);
    }
  };

  // prologue: stage tile 0
  stageKV(0, 0);
  if (w == 0) {
    unsigned long long mwb = __ballot(msk[b * Sv + l] != 0);
    if (l == 0) mword[0] = mwb;
  }
  __syncthreads();

  for (int kt = 0; kt < nkt; ++kt) {
    const int k0 = kt * 64;
    const int buf = kt & 1;
    // ---- prefetch tile kt+1 into the other buffer ----
    if (kt + 1 < nkt) {
      stageKV(kt + 1, buf ^ 1);
      if (w == 0) {
        unsigned long long mwb = __ballot(msk[b * Sv + (kt + 1) * 64 + l] != 0);
        if (l == 0) mword[buf ^ 1] = mwb;
      }
    }

    if (k0 <= q0 + 31) {   // wave has at least one valid row in this tile
      const unsigned long long mw = mword[buf];
      const char* kldsb = (const char*)Klds[buf];
      const char* vldsb = (const char*)Vlds[buf];
      // ---- QK^T ----
      f32x4 sacc[2][4] = {};
      __builtin_amdgcn_s_setprio(1);
#pragma unroll
      for (int kk = 0; kk < 2; ++kk) {
        s16x8 kf[4];
#pragma unroll
        for (int n = 0; n < 4; ++n) {
          int row = n * 16 + (l & 15);
          int sb = (row * 128 + kk * 64 + ((l >> 4) << 4)) ^ ((row & 7) << 4);
          kf[n] = *(s16x8*)(kldsb + sb);
        }
#pragma unroll
        for (int m = 0; m < 2; ++m)
#pragma unroll
          for (int n = 0; n < 4; ++n)
            sacc[m][n] = __builtin_amdgcn_mfma_f32_16x16x32_bf16(qf[m][kk], kf[n], sacc[m][n], 0, 0, 0);
      }
      __builtin_amdgcn_s_setprio(0);

      // ---- mask only where needed ----
      if ((k0 + 63 > q0) || (mw != 0)) {
#pragma unroll
        for (int m = 0; m < 2; ++m)
#pragma unroll
          for (int n = 0; n < 4; ++n)
#pragma unroll
            for (int e = 0; e < 4; ++e) {
              int kcol = n * 16 + (l & 15);
              int qg = q0 + m * 16 + ((l >> 4) << 2) + e;
              bool bad = (k0 + kcol > qg) || ((mw >> kcol) & 1ull);
              if (bad) sacc[m][n][e] = -1e30f;
            }
      }

      // ---- tile-global max (tree + 6 shfl, wave-uniform) ----
      float rmn[2][4];
#pragma unroll
      for (int m = 0; m < 2; ++m)
#pragma unroll
        for (int n = 0; n < 4; ++n)
          rmn[m][n] = fmaxf(fmaxf(sacc[m][n][0], sacc[m][n][1]),
                            fmaxf(sacc[m][n][2], sacc[m][n][3]));
      float rm = fmaxf(fmaxf(fmaxf(rmn[0][0], rmn[0][1]), fmaxf(rmn[0][2], rmn[0][3])),
                       fmaxf(fmaxf(rmn[1][0], rmn[1][1]), fmaxf(rmn[1][2], rmn[1][3])));
#pragma unroll
      for (int off = 1; off <= 32; off <<= 1)
        rm = fmaxf(rm, __shfl_xor(rm, off));

      if (rm > -1e29f) {           // tile not fully masked (wave-uniform)
        // ---- defer-rescale (T13) ----
        if (rm > mrun + 8.f) {
          float sc = EXP2(mrun - rm);   // first tile: 0
          mrun = rm;
#pragma unroll
          for (int m = 0; m < 2; ++m) {
            lacc[m] *= sc;
#pragma unroll
            for (int n = 0; n < 4; ++n) oacc[m][n] *= sc;
          }
        }

        // ---- P = exp2(s - mrun) -> per-wave LDS (bf16 trunc) ----
#pragma unroll
        for (int m = 0; m < 2; ++m)
#pragma unroll
          for (int n = 0; n < 4; ++n)
#pragma unroll
            for (int e = 0; e < 4; ++e) {
              float pv = EXP2(sacc[m][n][e] - mrun);
              int prow = m * 16 + ((l >> 4) << 2) + e;
              int pcol = n * 16 + (l & 15);
              int sb = (prow * 128 + pcol * 2) ^ ((prow & 7) << 4);
              *(short*)(pbase + sb) = (short)(__float_as_uint(pv) >> 16);
            }

        // ---- PV + row-sums (ones-MFMA) ----
        __builtin_amdgcn_s_setprio(1);
#pragma unroll
        for (int kk = 0; kk < 2; ++kk) {
          s16x8 pf[2], vf[4];
#pragma unroll
          for (int m = 0; m < 2; ++m) {
            int row = m * 16 + (l & 15);
            int sb = (row * 128 + kk * 64 + ((l >> 4) << 4)) ^ ((row & 7) << 4);
            pf[m] = *(s16x8*)(pbase + sb);
          }
#pragma unroll
          for (int n = 0; n < 4; ++n) {
            int row = n * 16 + (l & 15);
            int sb = (row * 128 + kk * 64 + ((l >> 4) << 4)) ^ ((row & 7) << 4);
            vf[n] = *(s16x8*)(vldsb + sb);
          }
#pragma unroll
          for (int m = 0; m < 2; ++m) {
#pragma unroll
            for (int n = 0; n < 4; ++n)
              oacc[m][n] = __builtin_amdgcn_mfma_f32_16x16x32_bf16(pf[m], vf[n], oacc[m][n], 0, 0, 0);
            lacc[m] = __builtin_amdgcn_mfma_f32_16x16x32_bf16(pf[m], onesf, lacc[m], 0, 0, 0);
          }
        }
        __builtin_amdgcn_s_setprio(0);
      }
    }
    __syncthreads();   // stage(kt+1) drained; all waves done with buf
  }

  // ---- epilogue: O /= rowsum, write AO [B,S,H] (bf16) ----
#pragma unroll
  for (int m = 0; m < 2; ++m)
#pragma unroll
    for (int e = 0; e < 4; ++e) {
      float inv = 1.f / lacc[m][e];
#pragma unroll
      for (int n = 0; n < 4; ++n) {
        int qg = q0 + m * 16 + ((l >> 4) << 2) + e;
        int dcol = n * 16 + (l & 15);
        AO[((size_t)b * Sv + qg) * Hv + h * HDv + dcol] = f2bf(oacc[m][n][e] * inv);
      }
    }
}

// ---------------------------------------------------------------------------
extern "C" void kernel_launch(void* const* d_in, const int* in_sizes, int n_in,
                              void* d_out, int out_size, void* d_ws, size_t ws_size,
                              hipStream_t stream) {
  (void)in_sizes; (void)n_in; (void)out_size; (void)ws_size;
  const float* x    = (const float*)d_in[0];
  const float* y    = (const float*)d_in[1];
  const unsigned char* msk = (const unsigned char*)d_in[2];
  const float* Wq   = (const float*)d_in[3];
  const float* Wqb  = (const float*)d_in[4];
  const float* Wkv  = (const float*)d_in[5];
  const float* Wkvb = (const float*)d_in[6];
  const float* Wo   = (const float*)d_in[7];
  const float* Wob  = (const float*)d_in[8];
  float* out = (float*)d_out;

  char* p = (char*)d_ws;
  auto alloc = [&](size_t bytes) {
    char* r = p;
    p += (bytes + 255) & ~(size_t)255;
    return r;
  };
  const size_t MT = (size_t)Bv * Sv;  // 8192
  short* Xb   = (short*)alloc(MT * Hv * 2);
  short* Yb   = (short*)alloc(MT * Hv * 2);
  short* Wt   = (short*)alloc((size_t)3 * Hv * Hv * 2);   // [Wq^T | Wkv^T] rows 0-3071
  short* Wot  = (short*)alloc((size_t)Hv * Hv * 2);
  short* Qb   = (short*)alloc(MT * Hv * 2);
  short* Kb   = (short*)alloc(MT * Hv * 2);
  short* Vb   = (short*)alloc(MT * Hv * 2);   // V^T [bh][d][s]
  short* AO   = (short*)alloc(MT * Hv * 2);

  const int n_x = (int)(MT * Hv);  // 8388608
  cvt2_bf16<<<2 * (n_x / 1024), 256, 0, stream>>>(x, y, Xb, Yb, n_x);
  tcvt<<<dim3(Hv / 32, Hv / 32), 256, 0, stream>>>(Wq, Wt, Hv, Hv);
  tcvt<<<dim3(2 * Hv / 32, Hv / 32), 256, 0, stream>>>(Wkv, Wt + (size_t)Hv * Hv, Hv, 2 * Hv);
  tcvt<<<dim3(Hv / 32, Hv / 32), 256, 0, stream>>>(Wo, Wot, Hv, Hv);

  gemm_qkv<<<dim3(MT / 128, 3 * Hv / 128), 256, 0, stream>>>(
      Xb, Yb, Wt, Wqb, Wkvb, Qb, Kb, Vb);

  attn_mfma<<<16 * 64, 256, 0, stream>>>(Qb, Kb, Vb, msk, AO);

  gemm_out<<<dim3(MT / 128, Hv / 128), 256, 0, stream>>>(
      AO, Wot, Wob, out, (int)MT, Hv, Hv);
}